// Round 23
// baseline (141.839 us; speedup 1.0000x reference)
//
#include <hip/hip_runtime.h>
#include <hip/hip_bf16.h>

typedef __attribute__((ext_vector_type(8))) short short8;
typedef __attribute__((ext_vector_type(4))) float f32x4;

#define MFMA16(a,b,c) __builtin_amdgcn_mfma_f32_16x16x32_bf16((a),(b),(c),0,0,0)

static __device__ __forceinline__ unsigned int f2bf(float f){
    unsigned int u = __float_as_uint(f);
    u += 0x7FFFu + ((u >> 16) & 1u);
    return u >> 16;
}

static __device__ __forceinline__ short8 pack8(float4 a, float4 b){
    short8 r;
    r[0]=(short)f2bf(a.x); r[1]=(short)f2bf(a.y);
    r[2]=(short)f2bf(a.z); r[3]=(short)f2bf(a.w);
    r[4]=(short)f2bf(b.x); r[5]=(short)f2bf(b.y);
    r[6]=(short)f2bf(b.z); r[7]=(short)f2bf(b.w);
    return r;
}

// ---------------- Merged: QKV projection (blocks 0..383) +
//                  mask bit-pack (blocks 384..1407) -----------------------
__global__ __launch_bounds__(256) void qkv_mask_k(
    const float* __restrict__ nd,
    const float* __restrict__ Wqp, const float* __restrict__ bqp,
    const float* __restrict__ Wkp, const float* __restrict__ bkp,
    const float* __restrict__ Wvp, const float* __restrict__ bvp,
    unsigned short* __restrict__ qout, unsigned short* __restrict__ kout,
    unsigned short* __restrict__ vtout,
    const unsigned int* __restrict__ m, unsigned int* __restrict__ bmout)
{
    __shared__ __align__(16) unsigned short xl[64*264];
    const int tid  = threadIdx.x;

    if (blockIdx.x >= 384){
        // ------- mask path (1024 blocks): dtype sniff + bit-pack -------
        __shared__ int any_hi;
        const int lane = tid & 63;
        const unsigned int gbase = (blockIdx.x - 384)*256u + tid;
        if (tid == 0) any_hi = 0;
        unsigned int wv[8]; unsigned int acc = 0;
        #pragma unroll
        for (int it = 0; it < 8; ++it){
            wv[it] = __builtin_nontemporal_load(m + it*262144u + gbase);
            acc |= wv[it];
        }
        __syncthreads();
        if (acc & 0xFFFFFF00u) atomicOr(&any_hi, 1);
        __syncthreads();
        if (any_hi == 0){
            for (int it = 0; it < 32; ++it){
                unsigned int idx = it*262144u + gbase;
                unsigned int v = __builtin_nontemporal_load(m + idx);
                unsigned long long bal = __ballot(v != 0u);
                if (lane == 0)
                    *(unsigned long long*)(bmout + (idx >> 5)) = bal;
            }
        } else {
            #pragma unroll
            for (int it = 0; it < 8; ++it){
                unsigned int idx = it*262144u + gbase;
                unsigned int v = wv[it];
                unsigned int nib = (v | (v>>7) | (v>>14) | (v>>21)) & 0xFu;
                unsigned int x = nib << ((lane & 7)*4);
                x |= (unsigned int)__shfl_xor((int)x, 1);
                x |= (unsigned int)__shfl_xor((int)x, 2);
                x |= (unsigned int)__shfl_xor((int)x, 4);
                if ((lane & 7) == 0)
                    bmout[idx >> 3] = x;
            }
        }
        return;
    }

    // ---------------- qkv path (blocks 0..383) ----------------
    const int bi   = blockIdx.x;          // 384 = 3 kinds x 128 tiles
    const int kind = bi >> 7;
    const int R0   = (bi & 127) * 64;
    const int b    = R0 >> 10;
    const int n0   = R0 & 1023;

    #pragma unroll
    for (int it = 0; it < 16; ++it){
        int f4 = it*256 + tid;
        int r = f4 >> 6, c4 = f4 & 63;
        float4 v = *(const float4*)(nd + (size_t)(R0+r)*256 + c4*4);
        unsigned int lo = f2bf(v.x) | (f2bf(v.y) << 16);
        unsigned int hi = f2bf(v.z) | (f2bf(v.w) << 16);
        *(uint2*)&xl[r*264 + c4*4] = make_uint2(lo, hi);
    }
    __syncthreads();

    const int lane = tid & 63;
    const int w  = tid >> 6;
    const int ln = lane & 15;
    const int g  = lane >> 4;
    const int ow = w * 64;

    f32x4 acc[4][4];
    #pragma unroll
    for (int a=0;a<4;++a){
        #pragma unroll
        for (int c=0;c<4;++c) acc[a][c] = (f32x4){0.f,0.f,0.f,0.f};
    }

    if (kind < 2){
        const float* W  = kind ? Wkp : Wqp;
        const float* bb = kind ? bkp : bqp;
        unsigned short* op = kind ? kout : qout;
        const float scl = kind ? 1.0f : 0.17677669529663687f;
        for (int kk = 0; kk < 8; ++kk){
            short8 wf[4], xf[4];
            #pragma unroll
            for (int ot=0; ot<4; ++ot){
                const float* wp = W + (size_t)(ow + ot*16 + ln)*256 + kk*32 + g*8;
                wf[ot] = pack8(*(const float4*)wp, *(const float4*)(wp+4));
            }
            #pragma unroll
            for (int nt=0; nt<4; ++nt)
                xf[nt] = *(const short8*)&xl[(nt*16+ln)*264 + kk*32 + g*8];
            #pragma unroll
            for (int ot=0; ot<4; ++ot){
                #pragma unroll
                for (int nt=0; nt<4; ++nt)
                    acc[ot][nt] = MFMA16(wf[ot], xf[nt], acc[ot][nt]);
            }
        }
        #pragma unroll
        for (int ot=0; ot<4; ++ot){
            int o0 = ow + ot*16 + g*4;
            int h = o0 >> 5, d0 = o0 & 31;
            float4 b4 = *(const float4*)(bb + o0);
            #pragma unroll
            for (int nt=0; nt<4; ++nt){
                int n = n0 + nt*16 + ln;
                unsigned int lo = f2bf((acc[ot][nt][0]+b4.x)*scl) | (f2bf((acc[ot][nt][1]+b4.y)*scl)<<16);
                unsigned int hi = f2bf((acc[ot][nt][2]+b4.z)*scl) | (f2bf((acc[ot][nt][3]+b4.w)*scl)<<16);
                *(uint2*)(op + ((size_t)(b*8+h)*1024 + n)*32 + d0) = make_uint2(lo,hi);
            }
        }
    } else {
        for (int kk = 0; kk < 8; ++kk){
            short8 wf[4], xf[4];
            #pragma unroll
            for (int ot=0; ot<4; ++ot){
                const float* wp = Wvp + (size_t)(ow + ot*16 + ln)*256 + kk*32 + g*8;
                wf[ot] = pack8(*(const float4*)wp, *(const float4*)(wp+4));
            }
            #pragma unroll
            for (int nt=0; nt<4; ++nt)
                xf[nt] = *(const short8*)&xl[(nt*16+ln)*264 + kk*32 + g*8];
            #pragma unroll
            for (int nt=0; nt<4; ++nt){
                #pragma unroll
                for (int ot=0; ot<4; ++ot)
                    acc[nt][ot] = MFMA16(xf[nt], wf[ot], acc[nt][ot]);
            }
        }
        #pragma unroll
        for (int nt=0; nt<4; ++nt){
            int nb = n0 + nt*16 + g*4;
            #pragma unroll
            for (int ot=0; ot<4; ++ot){
                int o = ow + ot*16 + ln;
                int h = o >> 5, d = o & 31;
                float bvv = bvp[o];
                unsigned int lo = f2bf(acc[nt][ot][0]+bvv) | (f2bf(acc[nt][ot][1]+bvv)<<16);
                unsigned int hi = f2bf(acc[nt][ot][2]+bvv) | (f2bf(acc[nt][ot][3]+bvv)<<16);
                *(uint2*)(vtout + ((size_t)(b*8+h)*32 + d)*1024 + nb) = make_uint2(lo,hi);
            }
        }
    }
}

// ---------------- Fused biased-masked attention (r23) ----------------
// Duty-cycle structure x lean compute (the untested matrix cell):
// DOUBLE-buffered bias LDS (2 x [8h][16q][36] = 36.9 KB), ONE no-drain
// barrier per 32-key chunk. Per iter: STAGE(bias c+1 -> OTHER buf, regs
// issued last iter) || issue LOADB(c+2) || COMPUTE(c, current buf).
// Bias loads are always in flight through compute -> HBM duty cycle ~1.
// K/V/mask lazy-loaded from L2 inside compute (no prefetch regs needed).
// kperm zero-shuffle + b128 bias reads + fixed-max softmax (r14-proven).
#define BARRIER_NODRAIN() \
    asm volatile("s_waitcnt lgkmcnt(0)\n\ts_barrier" ::: "memory")

__global__ __launch_bounds__(512, 4) void attn_k(
    const unsigned short* __restrict__ qbuf, const unsigned short* __restrict__ kbuf,
    const unsigned short* __restrict__ vtbuf, const float* __restrict__ bias,
    const unsigned int* __restrict__ bm, unsigned short* __restrict__ ab)
{
    __shared__ __align__(16) float bs[9216];   // 2 x [8h][16q][36] = 36.9 KB
    const int tid  = threadIdx.x;
    const int bi   = blockIdx.x;        // 512 = 8 b * 64 q-tiles
    const int b    = bi >> 6;
    const int q0   = (bi & 63) * 16;
    const int lane = tid & 63;
    const int w    = tid >> 6;          // wave = head
    const int ln   = lane & 15;
    const int g    = lane >> 4;

    // Q fragment (B-operand): col=q=ln, k=d=g*8..
    const short8 qf = *(const short8*)(qbuf + ((size_t)(b*8+w)*1024 + q0 + ln)*32 + g*8);

    // kperm: tile-local row ln -> key 8*(ln>>2)+(ln&3); S^T keys/lane = 8g+j
    const int kperm = ((ln >> 2) << 3) + (ln & 3);
    const unsigned short* kp = kbuf  + ((size_t)(b*8+w)*1024 + kperm)*32 + g*8;
    const unsigned short* vp = vtbuf + ((size_t)(b*8+w)*32   + ln)*1024 + g*8;
    const unsigned int*  bmp = bm + (size_t)(b*1024 + q0 + ln)*32;

    // bias staging (16KB/chunk): thread t covers q'=t>>5 (32 thr/row);
    // 2 float4 at row-chunk offsets (t&31)*4 and +128. h'=(t&1)*4, k'=(t&31)>>1
    const int sq  = tid >> 5;
    const float* bgp = bias + (size_t)(b*1024 + q0 + sq)*8192 + (tid & 31)*4;
    const int hqb = (tid & 1)*4*576 + sq*36;           // LDS write base (words)
    const int kpw = (tid & 31) >> 1;                   // k' within 16-block
    // bias read base: [h=w][q=ln][k]: 2x b128 at +8g, +8g+4
    const int rb0 = w*576 + ln*36 + 8*g;

    f32x4 acc0 = (f32x4){0.f,0.f,0.f,0.f};
    f32x4 acc1 = (f32x4){0.f,0.f,0.f,0.f};
    float lsum = 0.f;
    const f32x4 z4 = {0.f,0.f,0.f,0.f};

    f32x4 br0, br1;                    // rotating bias register set

#define LOADB(cc) do { int c_ = (cc); \
    br0 = __builtin_nontemporal_load((const f32x4*)(bgp + (size_t)c_*256)); \
    br1 = __builtin_nontemporal_load((const f32x4*)(bgp + (size_t)c_*256 + 128)); } while(0)

#define STAGE_TO(BUF) do { float* bb_ = bs + (BUF)*4608; \
    { int kw_ = kpw;      bb_[hqb+kw_]=br0[0]; bb_[hqb+576+kw_]=br0[1]; \
                          bb_[hqb+1152+kw_]=br0[2]; bb_[hqb+1728+kw_]=br0[3]; } \
    { int kw_ = 16+kpw;   bb_[hqb+kw_]=br1[0]; bb_[hqb+576+kw_]=br1[1]; \
                          bb_[hqb+1152+kw_]=br1[2]; bb_[hqb+1728+kw_]=br1[3]; } } while(0)

// 32-key chunk c from buffer BUF: lazy K/V/bm (L2), b128 bias, exp, PV
#define COMPUTE(C, BUF) do { int c_ = (C); \
    short8 kf0 = *(const short8*)(kp + c_*1024); \
    short8 kf1 = *(const short8*)(kp + c_*1024 + 128); \
    unsigned int bmw_ = bmp[c_]; \
    if (c_ == 0) bmw_ &= ~1u;           /* col 0 force-unmasked */ \
    f32x4 s0 = MFMA16(kf0, qf, z4);     /* keys 8g+0..3 */ \
    f32x4 s1 = MFMA16(kf1, qf, z4);     /* keys 8g+4..7 */ \
    const float* bb_ = bs + (BUF)*4608; \
    f32x4 blo = *(const f32x4*)&bb_[rb0]; \
    f32x4 bhi = *(const f32x4*)&bb_[rb0 + 4]; \
    short8 vf0 = *(const short8*)(vp + c_*32); \
    short8 vf1 = *(const short8*)(vp + c_*32 + 16*1024); \
    unsigned int mb_ = bmw_ >> (g*8); \
    float e0 = __expf(s0[0] + blo[0]); e0 = ((mb_>>0)&1u) ? 0.f : e0; \
    float e1 = __expf(s0[1] + blo[1]); e1 = ((mb_>>1)&1u) ? 0.f : e1; \
    float e2 = __expf(s0[2] + blo[2]); e2 = ((mb_>>2)&1u) ? 0.f : e2; \
    float e3 = __expf(s0[3] + blo[3]); e3 = ((mb_>>3)&1u) ? 0.f : e3; \
    float e4 = __expf(s1[0] + bhi[0]); e4 = ((mb_>>4)&1u) ? 0.f : e4; \
    float e5 = __expf(s1[1] + bhi[1]); e5 = ((mb_>>5)&1u) ? 0.f : e5; \
    float e6 = __expf(s1[2] + bhi[2]); e6 = ((mb_>>6)&1u) ? 0.f : e6; \
    float e7 = __expf(s1[3] + bhi[3]); e7 = ((mb_>>7)&1u) ? 0.f : e7; \
    lsum += ((e0+e1)+(e2+e3)) + ((e4+e5)+(e6+e7)); \
    int4 pw_ = make_int4( \
        (int)(f2bf(e0) | (f2bf(e1)<<16)), (int)(f2bf(e2) | (f2bf(e3)<<16)), \
        (int)(f2bf(e4) | (f2bf(e5)<<16)), (int)(f2bf(e6) | (f2bf(e7)<<16))); \
    short8 pf_ = *(short8*)&pw_; \
    acc0 = MFMA16(vf0, pf_, acc0); \
    acc1 = MFMA16(vf1, pf_, acc1); } while(0)

    // prologue: stage chunk 0 into buf0; chunk 1 in flight
    LOADB(0);
    STAGE_TO(0);                        // counted-vmcnt wait for chunk-0 regs
    LOADB(1);
    BARRIER_NODRAIN();

    #pragma unroll 1
    for (int c = 0; c < 32; ++c){
        const int cur = c & 1;
        if (c + 1 < 32) STAGE_TO(cur ^ 1);   // bias(c+1) -> other buffer
        if (c + 2 < 32) LOADB(c + 2);        // flies through compute+barrier
        COMPUTE(c, cur);                      // reads current buffer
        BARRIER_NODRAIN();
    }

    float ps = lsum;
    ps += __shfl_xor(ps, 16);
    ps += __shfl_xor(ps, 32);
    float inv = 1.0f / ps;
    {
        int n = q0 + ln;
        unsigned int lo0 = f2bf(acc0[0]*inv) | (f2bf(acc0[1]*inv)<<16);
        unsigned int hi0 = f2bf(acc0[2]*inv) | (f2bf(acc0[3]*inv)<<16);
        *(uint2*)(ab + ((size_t)(b*1024 + n))*256 + w*32 + g*4) = make_uint2(lo0,hi0);
        unsigned int lo1 = f2bf(acc1[0]*inv) | (f2bf(acc1[1]*inv)<<16);
        unsigned int hi1 = f2bf(acc1[2]*inv) | (f2bf(acc1[3]*inv)<<16);
        *(uint2*)(ab + ((size_t)(b*1024 + n))*256 + w*32 + 16 + g*4) = make_uint2(lo1,hi1);
    }
#undef LOADB
#undef STAGE_TO
#undef COMPUTE
}

// ---------------- Output projection (32-row tiles) ----------------
__global__ __launch_bounds__(256) void oproj_k(
    const unsigned short* __restrict__ ab, const float* __restrict__ Wop,
    const float* __restrict__ bop, float* __restrict__ out)
{
    __shared__ __align__(16) unsigned short al[32*264];
    const int tid = threadIdx.x;
    const int R0 = blockIdx.x * 32;   // 256 blocks
    #pragma unroll
    for (int it=0; it<4; ++it){
        int f8 = it*256 + tid;
        int r = f8 >> 5, c8 = f8 & 31;
        *(short8*)&al[r*264 + c8*8] = *(const short8*)(ab + (size_t)(R0+r)*256 + c8*8);
    }
    __syncthreads();
    const int lane = tid & 63;
    const int w = tid >> 6, ln = lane & 15, g = lane >> 4;
    const int ow = w*64;
    f32x4 acc[4][2];
    #pragma unroll
    for (int a=0;a<4;++a){ acc[a][0]=(f32x4){0.f,0.f,0.f,0.f}; acc[a][1]=(f32x4){0.f,0.f,0.f,0.f}; }
    for (int kk=0;kk<8;++kk){
        short8 wf[4], xf[2];
        #pragma unroll
        for (int ot=0;ot<4;++ot){
            const float* wp = Wop + (size_t)(ow+ot*16+ln)*256 + kk*32 + g*8;
            wf[ot] = pack8(*(const float4*)wp, *(const float4*)(wp+4));
        }
        #pragma unroll
        for (int nt=0;nt<2;++nt)
            xf[nt] = *(const short8*)&al[(nt*16+ln)*264 + kk*32 + g*8];
        #pragma unroll
        for (int ot=0;ot<4;++ot){
            #pragma unroll
            for (int nt=0;nt<2;++nt)
                acc[ot][nt] = MFMA16(wf[ot], xf[nt], acc[ot][nt]);
        }
    }
    #pragma unroll
    for (int ot=0;ot<4;++ot){
        int o0 = ow + ot*16 + g*4;
        float4 b4 = *(const float4*)(bop + o0);
        #pragma unroll
        for (int nt=0;nt<2;++nt){
            int n = R0 + nt*16 + ln;
            float4 res;
            res.x = acc[ot][nt][0] + b4.x;
            res.y = acc[ot][nt][1] + b4.y;
            res.z = acc[ot][nt][2] + b4.z;
            res.w = acc[ot][nt][3] + b4.w;
            *(float4*)(out + (size_t)n*256 + o0) = res;
        }
    }
}

extern "C" void kernel_launch(void* const* d_in, const int* in_sizes, int n_in,
                              void* d_out, int out_size, void* d_ws, size_t ws_size,
                              hipStream_t stream)
{
    (void)in_sizes; (void)n_in; (void)out_size; (void)ws_size;
    const float* nd   = (const float*)d_in[0];
    // d_in[1] = N scalar (compile-time 1024 here)
    const float* bias = (const float*)d_in[2];
    const int* mask   = (const int*)d_in[3];
    const float* Wq = (const float*)d_in[4];
    const float* bq = (const float*)d_in[5];
    const float* Wk = (const float*)d_in[6];
    const float* bk = (const float*)d_in[7];
    const float* Wv = (const float*)d_in[8];
    const float* bv = (const float*)d_in[9];
    const float* Wo = (const float*)d_in[10];
    const float* bo = (const float*)d_in[11];
    float* out = (float*)d_out;

    const size_t ELEMS = (size_t)8*8*1024*32;   // 2M bf16 per buffer
    unsigned short* qb  = (unsigned short*)d_ws;
    unsigned short* kb  = qb  + ELEMS;
    unsigned short* vtb = kb  + ELEMS;
    unsigned short* ab  = vtb + ELEMS;
    unsigned int* bmw   = (unsigned int*)(ab + ELEMS);  // 1MB bitmask

    qkv_mask_k<<<1408, 256, 0, stream>>>(nd, Wq, bq, Wk, bk, Wv, bv,
                                         qb, kb, vtb,
                                         (const unsigned int*)mask, bmw);
    attn_k<<<512, 512, 0, stream>>>(qb, kb, vtb, bias, bmw, ab);
    oproj_k<<<256, 256, 0, stream>>>(ab, Wo, bo, out);
}